// Round 14
// baseline (15021.620 us; speedup 1.0000x reference)
//
#include <hip/hip_runtime.h>
#include <hip/hip_cooperative_groups.h>
#include <stdint.h>
#include <stddef.h>

namespace cg = cooperative_groups;

// ---------------------------------------------------------------------------
// Seq2Seq LSTM, MI355X persistent cooperative kernel.
// B=256, S=512, F=64, H=1024, T=64.  f32 I/O, bf16 MFMA internals.
//
// R26 -> R27: RERUN. R26 never executed (GPU acquisition timeout). Kernel
// byte-identical to R26: DVFS disambiguation via UNCONDITIONAL,
// latency-hidden heat.
// R25 fact: VALUBusy 4.07->4.33% with poll-gated filler => polls succeed on
// first check => nobody waits on communication readiness; per-step time is
// the WG's own body (load RTT + drain + barriers + compute) at sustained
// clock. The DVFS theory was never tested (filler never ran).
// Two live hypotheses:
//   H-A: clock ~540 MHz (MfmaUtil per-SIMD math; 3x dispatch-to-dispatch
//        variance on identical code supports clock-state sensitivity).
//   H-B: clock ~2.2 GHz and ~54K cyc/step of pathological latency.
// Test: ~1.5-3K cyc dual-accumulator VALU chain (not DCE-able) inserted
// AFTER issuing the 17 h-loads, BEFORE their first MFMA use -- executes
// under in-flight load RTT (free under both hypotheses), raises SIMD
// activity ~4% -> 15-30%. H-A predicts dur collapses to ~5-9ms; H-B
// predicts flat (+<0.5ms). Either outcome decides the next move.
// Everything else byte-identical to R25 (dataflow stamps, no barrier).
//
// 256 WGs = 4 batch-groups (m) x 64 gate-slices (n). 512 thr / 8 waves;
// wave = (mh, q): gates M32xN64x17ksteps, decoder M32xN64x16ksteps.
// Weights persistent in LDS (139 KB). h ring n-major, per-WG 2KB block.
// ---------------------------------------------------------------------------

typedef short s16x8 __attribute__((ext_vector_type(8)));
typedef float f32x4 __attribute__((ext_vector_type(4)));
typedef float f32x16 __attribute__((ext_vector_type(16)));

#define LDS_BYTES  156416
#define RED_OFF    139264   // 64x65 f32 reduction buffer
#define BIASG_OFF  155904   // 64 f32 gate bias
#define BIASFC_OFF 156160   // 64 f32 fc bias

// workspace layout (bytes)
#define WS_FLAGS 0          // stamps: 4m x 64n x 32B = 8192 B (< 12288 pad)
#define WS_HRING 12288      // 8 x 524288 B (ring of 256x1024 bf16 buffers)
#define WS_WFC   4206592    // 131072 B (64x1024 bf16)
// total: 4337664 B

#define HBUF_ELEMS 262144   // 256*1024 bf16 elements per ring buffer

// stamp slot word index: 32B stride; 4x16 digit swap spreads contiguous
// slice indices across lines (both writer and readers use this map).
#define SLOT(mm,nn) (((mm) * 64 + ((((nn) & 15) << 2) | ((nn) >> 4))) * 8)

// Poll-gated filler (kept from R25; rarely runs).
__device__ __forceinline__ void spin_filler() {
  float x = 1.0f;
#pragma unroll
  for (int i = 0; i < 64; ++i)
    asm volatile("v_add_f32 %0, %0, %0" : "+v"(x));
}

// UNCONDITIONAL heat: two interleaved dependent chains -> ~1 VALU issue
// every 2 cyc for ~2*N instructions. N=384 pairs => 768 v_adds, ~1.5-3K cyc.
// Placed under in-flight load latency; touches only private regs.
__device__ __forceinline__ void heat() {
  float x = 1.0f, y = 2.0f;
#pragma unroll
  for (int i = 0; i < 384; ++i)
    asm volatile("v_add_f32 %0, %0, %0\n\tv_add_f32 %1, %1, %1"
                 : "+v"(x), "+v"(y));
}

__device__ __forceinline__ unsigned short f2bf(float f) {
  union { unsigned int i; float f; } v;
  v.f = f;
  unsigned int i = v.i;
  return (unsigned short)((i + 0x7FFFu + ((i >> 16) & 1u)) >> 16);
}
__device__ __forceinline__ float sigm(float x) { return 1.f / (1.f + __expf(-x)); }
__device__ __forceinline__ float tanh_f(float x) {
  float e = __expf(2.f * x);
  return 1.f - 2.f / (e + 1.f);
}

// Stage this WG's weight slice (f32 global -> bf16 LDS, MFMA-B fragment
// order). 8 waves (f += 8).
__device__ __forceinline__ void load_wg(unsigned short* wl, float* biasg,
    const float* Wih, const float* Whh, const float* bih, const float* bhh,
    int n, int wave, int lane, int tid) {
  const int l31 = lane & 31;
  const int kh8 = (lane >> 5) << 3;
  for (int f = wave; f < 136; f += 8) {
    const int s  = f >> 1;
    const int t2 = f & 1;
    const int col = t2 * 32 + l31;
    const int k0  = s * 16 + kh8;
    const int r   = (col >> 4) * 1024 + n * 16 + (col & 15);
    const float* src = (s < 4) ? (Wih + (size_t)r * 64 + k0)
                               : (Whh + (size_t)r * 1024 + (k0 - 64));
    s16x8 w;
#pragma unroll
    for (int j = 0; j < 8; ++j) ((unsigned short*)&w)[j] = f2bf(src[j]);
    *(s16x8*)(wl + (size_t)f * 512 + lane * 8) = w;
  }
  if (tid < 64) {
    const int r = (tid >> 4) * 1024 + n * 16 + (tid & 15);
    biasg[tid] = bih[r] + bhh[r];
  }
}

// C/D layout (m74/m101-verified): col = lane&31,
// row = (r&3) + 8*(r>>2) + 4*(lane>>5), r in [0,16). mh = M-half (0/1).
__device__ __forceinline__ void red_write32(float* red, const f32x16 (&acc)[2],
                                            int lane, int mh, const float* bias) {
#pragma unroll
  for (int t2 = 0; t2 < 2; ++t2)
#pragma unroll
    for (int r = 0; r < 16; ++r) {
      const int row = mh * 32 + (r & 3) + ((r >> 2) << 3) + ((lane >> 5) << 2);
      const int col = t2 * 32 + (lane & 31);
      float v = acc[t2][r];
      if (bias) v += bias[col];
      red[row * 65 + col] = v;
    }
}
__device__ __forceinline__ void red_add32(float* red, const f32x16 (&acc)[2],
                                          int lane, int mh) {
#pragma unroll
  for (int t2 = 0; t2 < 2; ++t2)
#pragma unroll
    for (int r = 0; r < 16; ++r) {
      const int row = mh * 32 + (r & 3) + ((r >> 2) << 3) + ((lane >> 5) << 2);
      const int col = t2 * 32 + (lane & 31);
      atomicAdd(red + row * 65 + col, acc[t2][r]);
    }
}

__global__ void __launch_bounds__(512, 1) seq2seq_lstm(
    const float* __restrict__ xin,
    const float* __restrict__ Wih_e,
    const float* __restrict__ Whh_e,
    const float* __restrict__ bih_e,
    const float* __restrict__ bhh_e,
    const float* __restrict__ Wih_d,
    const float* __restrict__ Whh_d,
    const float* __restrict__ bih_d,
    const float* __restrict__ bhh_d,
    const float* __restrict__ Wfc,
    const float* __restrict__ bfc,
    float* __restrict__ out,
    unsigned short* __restrict__ hring,
    unsigned short* __restrict__ wfcb,
    unsigned int* __restrict__ flags) {
  extern __shared__ char smem[];
  unsigned short* wl = (unsigned short*)smem;
  float* red    = (float*)(smem + RED_OFF);
  float* biasg  = (float*)(smem + BIASG_OFF);
  float* biasfc = (float*)(smem + BIASFC_OFF);

  cg::grid_group grid = cg::this_grid();

  const int tid  = threadIdx.x;
  const int wave = tid >> 6;   // 0..7
  const int lane = tid & 63;
  const int wg   = blockIdx.x;
  const int m    = wg & 3;     // batch-group (XCD-locality swizzle)
  const int n    = wg >> 2;    // gate-slice
  const int bm   = m << 6;
  const int l31  = lane & 31;
  const int kh8  = (lane >> 5) << 3;
  const int mh   = wave & 1;   // M-half (rows mh*32..mh*32+31)
  const int q    = wave >> 1;  // K-quarter
  const int ks0  = q * 17;     // gates: this wave's k-step base (of 68)
  const int mrow = bm + mh * 32 + l31; // this lane's A row
  // activation mapping (tid < 256): row ar = tid>>2, units auu..auu+3
  const int ar   = tid >> 2;
  const int auu  = (tid & 3) << 2;

  load_wg(wl, biasg, Wih_e, Whh_e, bih_e, bhh_e, n, wave, lane, tid);

  // In-kernel init: zero ring buffer 7 (h_{-1}, this WG's n-major slice);
  // zero own stamp slot; convert W_fc slice. grid.sync publishes.
  {
    if (tid < 256) {
      unsigned short* hinit = hring + (size_t)7 * HBUF_ELEMS;
      const size_t hq = ((size_t)n * 4096 + (size_t)(bm + ar) * 16 + auu) >> 2;
      __hip_atomic_store((unsigned long long*)hinit + hq, 0ull,
                         __ATOMIC_RELAXED, __HIP_MEMORY_SCOPE_AGENT);
      wfcb[wg * 256 + tid] = f2bf(Wfc[wg * 256 + tid]);
    }
    if (tid == 0)
      __hip_atomic_store(flags + SLOT(m, n), 0u,
                         __ATOMIC_RELAXED, __HIP_MEMORY_SCOPE_AGENT);
  }
  __syncthreads();
  grid.sync(); // one-time full-coherence publish of init state

  float cst[4] = {0.f, 0.f, 0.f, 0.f};

  for (int gs = 0; gs < 576; ++gs) {
    const bool dec = (gs >= 512);
    const int t = gs - 512;

    // ---- amortized acquire fence: every 8 steps, before any h read ----
    if ((gs & 7) == 0 && gs != 0) {
      if (tid == 0) __builtin_amdgcn_fence(__ATOMIC_ACQUIRE, "agent");
      __syncthreads();
    }

    if (gs == 512) {
      __syncthreads();
      load_wg(wl, biasg, Wih_d, Whh_d, bih_d, bhh_d, n, wave, lane, tid);
      if (tid < 64) biasfc[tid] = bfc[tid];
      __syncthreads();
    }
    const unsigned short* hb = hring + (size_t)((gs + 7) & 7) * HBUF_ELEMS; // h_{gs-1}
    unsigned short* hnx      = hring + (size_t)(gs & 7) * HBUF_ELEMS;       // h_gs

    // ---- per-wave dataflow wait (rarely loops -- R25 evidence) ----
    {
      const int s = ks0 + lane;
      const bool need = (lane < 17) && (s >= 4);
      unsigned int* sp = flags + (need ? SLOT(m, s - 4) : SLOT(m, 0));
      const unsigned int thr = (unsigned int)gs;
      for (;;) {
        unsigned int v = need ? __hip_atomic_fetch_add(sp, 0u, __ATOMIC_RELAXED,
                                                       __HIP_MEMORY_SCOPE_AGENT)
                              : thr;
        if (__all((int)(v >= thr))) break;
        spin_filler();
      }
      __builtin_amdgcn_fence(__ATOMIC_ACQUIRE, "workgroup"); // no load hoisting
    }

    // ---- prefetch A fragments for this wave's (M-half, K-quarter) ----
    s16x8 areg[17];
#pragma unroll
    for (int i = 0; i < 17; ++i) {
      const int s = ks0 + i;
      if (s < 4) { // x part (K 0..63) — only waves 0,1 (q==0)
        const int fk = s * 16 + kh8;
        if (!dec || t == 0) {
          const int tt = dec ? 511 : gs;
          const float* p = xin + (size_t)mrow * 32768 + tt * 64 + fk;
          s16x8 av;
#pragma unroll
          for (int j = 0; j < 8; ++j) ((unsigned short*)&av)[j] = f2bf(p[j]);
          areg[i] = av;
        } else { // x = previous pred, in red (f32); rows mh*32+l31
          s16x8 av;
#pragma unroll
          for (int j = 0; j < 8; ++j)
            ((unsigned short*)&av)[j] = f2bf(red[(mh * 32 + l31) * 65 + fk + j]);
          areg[i] = av;
        }
      } else { // h part (K 64..1087): n-major ring: elem=(s-4)*4096+row*16+kh8
        areg[i] = *(const s16x8*)(hb + (size_t)(s - 4) * 4096 +
                                  (size_t)mrow * 16 + kh8);
      }
    }

    // ---- UNCONDITIONAL heat, hidden under in-flight h-load latency:
    //      raises SIMD activity 4% -> 15-30% to test activity-driven DVFS.
    heat();

    // ---- gates GEMM: M32 x N64 x 17 ksteps (this wave) ----
    f32x16 acc[2] = {};
#pragma unroll
    for (int i = 0; i < 17; ++i) {
      const int s = ks0 + i;
      const s16x8 b0 = *(const s16x8*)(wl + (size_t)(s * 2 + 0) * 512 + lane * 8);
      const s16x8 b1 = *(const s16x8*)(wl + (size_t)(s * 2 + 1) * 512 + lane * 8);
      acc[0] = __builtin_amdgcn_mfma_f32_32x32x16_bf16(areg[i], b0, acc[0], 0, 0, 0);
      acc[1] = __builtin_amdgcn_mfma_f32_32x32x16_bf16(areg[i], b1, acc[1], 0, 0, 0);
    }

    // ---- cross-wave K reduction (waves q==0 write, q>0 add) ----
    if (q == 0) red_write32(red, acc, lane, mh, nullptr);
    __syncthreads();
    if (q != 0) red_add32(red, acc, lane, mh);
    __syncthreads();

    // ---- activation + state update (tid<256, 4 units/thread); write h as
    //      ONE u64 agent atomic per thread (R17-proven write-through) ----
    if (tid < 256) {
      float hn[4];
#pragma unroll
      for (int j = 0; j < 4; ++j) {
        const int u = auu + j;
        const float gi = red[ar * 65 + u]      + biasg[u];
        const float gf = red[ar * 65 + 16 + u] + biasg[16 + u];
        const float gg = red[ar * 65 + 32 + u] + biasg[32 + u];
        const float go = red[ar * 65 + 48 + u] + biasg[48 + u];
        const float c = sigm(gf) * cst[j] + sigm(gi) * tanh_f(gg);
        cst[j] = c;
        hn[j] = sigm(go) * tanh_f(c);
      }
      union { unsigned short u[4]; unsigned long long ull; } pk;
#pragma unroll
      for (int j = 0; j < 4; ++j) pk.u[j] = f2bf(hn[j]);
      const size_t hq = ((size_t)n * 4096 + (size_t)(bm + ar) * 16 + auu) >> 2;
      __hip_atomic_store((unsigned long long*)hnx + hq, pk.ull,
                         __ATOMIC_RELAXED, __HIP_MEMORY_SCOPE_AGENT);
    }
    __syncthreads(); // vmcnt drain: all h stores COMPLETE (ack'd) at LLC

    // ---- publish: fire-and-forget stamp (no wait, no barrier) ----
    if (tid == 0)
      __hip_atomic_store(flags + SLOT(m, n), (unsigned int)gs + 1u,
                         __ATOMIC_RELAXED, __HIP_MEMORY_SCOPE_AGENT);

    // ---- decoder: pred = h_new @ W_fc^T + b_fc; kept in red as next x;
    //      n==0 writes out. Per-wave wait for h_gs slices, then acquire
    //      fence (R6-proven), then M32 x N64 x 16 ksteps. ----
    if (dec && (n == 0 || t < 63)) {
      {
        const bool need = (lane < 16);
        const int sl = q * 16 + (lane & 15);
        unsigned int* sp = flags + SLOT(m, sl);
        const unsigned int thr = (unsigned int)gs + 1u;
        for (;;) {
          unsigned int v = need ? __hip_atomic_fetch_add(sp, 0u, __ATOMIC_RELAXED,
                                                         __HIP_MEMORY_SCOPE_AGENT)
                                : thr;
          if (__all((int)(v >= thr))) break;
          spin_filler();
        }
      }
      __syncthreads();
      if (tid == 0) __builtin_amdgcn_fence(__ATOMIC_ACQUIRE, "agent");
      __syncthreads();

      f32x16 pacc[2] = {};
      const int ps0 = q * 16;
#pragma unroll 4
      for (int i = 0; i < 16; ++i) {
        const int k = (ps0 + i) * 16 + kh8;
        const unsigned short* hp =
            hnx + (size_t)(ps0 + i) * 4096 + (size_t)mrow * 16 + kh8;
        const unsigned short* wp = wfcb + (size_t)l31 * 1024 + k;
        const s16x8 a0 = *(const s16x8*)hp;
        const s16x8 b0 = *(const s16x8*)wp;            // out cols 0..31
        const s16x8 b1 = *(const s16x8*)(wp + 32 * 1024); // out cols 32..63
        pacc[0] = __builtin_amdgcn_mfma_f32_32x32x16_bf16(a0, b0, pacc[0], 0, 0, 0);
        pacc[1] = __builtin_amdgcn_mfma_f32_32x32x16_bf16(a0, b1, pacc[1], 0, 0, 0);
      }
      if (q == 0) red_write32(red, pacc, lane, mh, biasfc);
      __syncthreads();
      if (q != 0) red_add32(red, pacc, lane, mh);
      __syncthreads();
      if (n == 0) {
        const int ob = tid >> 3;          // out row 0..63
        const int oc = (tid & 7) << 3;    // 8 cols per thread
        float* op = out + (size_t)(bm + ob) * 4096 + t * 64 + oc;
#pragma unroll
        for (int jj = 0; jj < 8; jj += 4) {
          f32x4 v = { red[ob * 65 + oc + jj],     red[ob * 65 + oc + jj + 1],
                      red[ob * 65 + oc + jj + 2], red[ob * 65 + oc + jj + 3] };
          *(f32x4*)(op + jj) = v;
        }
      }
      __syncthreads(); // red stable before next step's x reads
    }
  }
}

extern "C" void kernel_launch(void* const* d_in, const int* in_sizes, int n_in,
                              void* d_out, int out_size, void* d_ws, size_t ws_size,
                              hipStream_t stream) {
  (void)in_sizes; (void)n_in; (void)out_size; (void)ws_size;
  const float* xin   = (const float*)d_in[0];
  const float* Wih_e = (const float*)d_in[1];
  const float* Whh_e = (const float*)d_in[2];
  const float* bih_e = (const float*)d_in[3];
  const float* bhh_e = (const float*)d_in[4];
  const float* Wih_d = (const float*)d_in[5];
  const float* Whh_d = (const float*)d_in[6];
  const float* bih_d = (const float*)d_in[7];
  const float* bhh_d = (const float*)d_in[8];
  const float* Wfc   = (const float*)d_in[9];
  const float* bfc   = (const float*)d_in[10];
  float* out = (float*)d_out;

  char* ws = (char*)d_ws;
  unsigned int* flags   = (unsigned int*)(ws + WS_FLAGS);
  unsigned short* hring = (unsigned short*)(ws + WS_HRING);
  unsigned short* wfcb  = (unsigned short*)(ws + WS_WFC);

  hipFuncSetAttribute((const void*)seq2seq_lstm,
                      hipFuncAttributeMaxDynamicSharedMemorySize, LDS_BYTES);

  void* args[] = {
    (void*)&xin, (void*)&Wih_e, (void*)&Whh_e, (void*)&bih_e, (void*)&bhh_e,
    (void*)&Wih_d, (void*)&Whh_d, (void*)&bih_d, (void*)&bhh_d,
    (void*)&Wfc, (void*)&bfc, (void*)&out, (void*)&hring,
    (void*)&wfcb, (void*)&flags
  };
  hipLaunchCooperativeKernel((const void*)seq2seq_lstm, dim3(256), dim3(512),
                             args, LDS_BYTES, stream);
}